// Round 19
// baseline (299.779 us; speedup 1.0000x reference)
//
#include <hip/hip_runtime.h>

#define DD 48
#define TT 512
#define BB 512
#define PF 8
#define AWS_STRIDE 64
#define AWS_BYTES ((size_t)BB * TT * AWS_STRIDE * 4)   // 67,108,864
#define BPWS_BYTES ((size_t)BB * TT * DD)              // 12,582,912
#define WS_NEED (AWS_BYTES + BPWS_BYTES)

#define DPP_WAVE_ROR1 0x13C

__device__ __forceinline__ float readlane_f(float v, int lane) {
  return __int_as_float(__builtin_amdgcn_readlane(__float_as_int(v), lane));
}
template <int CTRL>
__device__ __forceinline__ float dpp_f(float v) {
  return __int_as_float(__builtin_amdgcn_mov_dpp(__float_as_int(v), CTRL, 0xF, 0xF, false));
}
__device__ __forceinline__ float bperm_f(int addr, float v) {
  return __int_as_float(__builtin_amdgcn_ds_bpermute(addr, __float_as_int(v)));
}
__device__ __forceinline__ float max3f(float a, float b, float c) {
  return fmaxf(fmaxf(a, b), c);
}

// value max over 64 slots (VCC-free, max3 tree)
__device__ __forceinline__ float vmax64(const float* p) {
  float m1[22];
#pragma unroll
  for (int k = 0; k < 21; ++k) m1[k] = max3f(p[3 * k], p[3 * k + 1], p[3 * k + 2]);
  m1[21] = p[63];
  float m2[8];
#pragma unroll
  for (int k = 0; k < 7; ++k) m2[k] = max3f(m1[3 * k], m1[3 * k + 1], m1[3 * k + 2]);
  m2[7] = m1[21];
  return max3f(max3f(m2[0], m2[1], m2[2]), max3f(m2[3], m2[4], m2[5]),
               fmaxf(m2[6], m2[7]));
}

// pure value max over 48 (fallback fwd)
__device__ __forceinline__ float vmax48(const float* s) {
  float m1[16];
#pragma unroll
  for (int k = 0; k < 16; ++k) m1[k] = max3f(s[3 * k], s[3 * k + 1], s[3 * k + 2]);
  float m2[6];
#pragma unroll
  for (int k = 0; k < 5; ++k) m2[k] = max3f(m1[3 * k], m1[3 * k + 1], m1[3 * k + 2]);
  m2[5] = m1[15];
  return fmaxf(max3f(m2[0], m2[1], m2[2]), max3f(m2[3], m2[4], m2[5]));
}

// argmax with first-index ties (strict > moves right)
__device__ __forceinline__ int argidx48(const float* s) {
  float v1[24]; int x1[24];
#pragma unroll
  for (int k = 0; k < 24; ++k) {
    float l = s[2 * k], r = s[2 * k + 1];
    v1[k] = fmaxf(l, r); x1[k] = (r > l) ? 2 * k + 1 : 2 * k;
  }
  float v2[12]; int x2[12];
#pragma unroll
  for (int k = 0; k < 12; ++k) {
    float l = v1[2 * k], r = v1[2 * k + 1];
    v2[k] = fmaxf(l, r); x2[k] = (r > l) ? x1[2 * k + 1] : x1[2 * k];
  }
  float v3[6]; int x3[6];
#pragma unroll
  for (int k = 0; k < 6; ++k) {
    float l = v2[2 * k], r = v2[2 * k + 1];
    v3[k] = fmaxf(l, r); x3[k] = (r > l) ? x2[2 * k + 1] : x2[2 * k];
  }
  float v4[3]; int x4[3];
#pragma unroll
  for (int k = 0; k < 3; ++k) {
    float l = v3[2 * k], r = v3[2 * k + 1];
    v4[k] = fmaxf(l, r); x4[k] = (r > l) ? x3[2 * k + 1] : x3[2 * k];
  }
  float vm = fmaxf(v4[0], v4[1]);
  int xm = (v4[1] > v4[0]) ? x4[1] : x4[0];
  return (v4[2] > vm) ? x4[2] : xm;
}

// ---- kernel 1: serial forward — 7 bpermute seeds + 8 independent depth-7 DPP chains ----
__global__ __launch_bounds__(64, 1) void crf_fwd(const float* __restrict__ logits,
                                                 const int* __restrict__ lens,
                                                 const float* __restrict__ trans,
                                                 float* __restrict__ aws) {
  const int b = blockIdx.x;
  const int j = threadIdx.x;
  const int jj = j < DD ? j : DD - 1;

  // probe rotation direction once (wave-uniform, branchless) — proven in R18
  const float w = dpp_f<DPP_WAVE_ROR1>((float)j);
  const bool dirp = (w == (float)((j + 1) & 63));

  // bpermute addresses for seeds c=1..7 (rotation by 8c)
  int ba[8];
#pragma unroll
  for (int c = 0; c < 8; ++c) {
    int sp = (j + 8 * c) & 63, sm = (j - 8 * c) & 63;
    ba[c] = (dirp ? sp : sm) * 4;
  }

  // slot table: slot 8c+k holds alpha[src], src = dirp ? (j+8c+k)&63 : (j-8c-k)&63
  float tS[64];
#pragma unroll
  for (int c = 0; c < 8; ++c) {
#pragma unroll
    for (int k = 0; k < 8; ++k) {
      int sp = (j + 8 * c + k) & 63, sm = (j - 8 * c - k) & 63;
      int src = dirp ? sp : sm;
      bool valid = (src < DD) && (j < DD);
      tS[8 * c + k] = valid ? trans[(src < DD ? src : 0) * DD + jj] : -1e30f;
    }
  }

  const float* lg = logits + (size_t)b * TT * DD;
  const int L = lens[b];

  float alpha = lg[jj];
  float* awsb = aws + (size_t)b * TT * AWS_STRIDE;
  awsb[j] = alpha; // row 0

  float e0 = lg[1 * DD + jj], e1 = lg[2 * DD + jj],
        e2 = lg[3 * DD + jj], e3 = lg[4 * DD + jj],
        e4 = lg[5 * DD + jj], e5 = lg[6 * DD + jj],
        e6 = lg[7 * DD + jj], e7 = lg[8 * DD + jj];

  // step: 7 independent bpermute seeds, then 8 independent depth-7 ror1 chains
#define STEP(EV)                                                   \
  {                                                                \
    float sd0 = alpha;                                             \
    float sd1 = bperm_f(ba[1], alpha);                             \
    float sd2 = bperm_f(ba[2], alpha);                             \
    float sd3 = bperm_f(ba[3], alpha);                             \
    float sd4 = bperm_f(ba[4], alpha);                             \
    float sd5 = bperm_f(ba[5], alpha);                             \
    float sd6 = bperm_f(ba[6], alpha);                             \
    float sd7 = bperm_f(ba[7], alpha);                             \
    float p[64];                                                   \
    float r0 = sd0, r1 = sd1, r2 = sd2, r3 = sd3,                  \
          r4 = sd4, r5 = sd5, r6 = sd6, r7 = sd7;                  \
    p[0] = r0 + tS[0];   p[8] = r1 + tS[8];                        \
    p[16] = r2 + tS[16]; p[24] = r3 + tS[24];                      \
    p[32] = r4 + tS[32]; p[40] = r5 + tS[40];                      \
    p[48] = r6 + tS[48]; p[56] = r7 + tS[56];                      \
    _Pragma("unroll")                                              \
    for (int k = 1; k < 8; ++k) {                                  \
      r0 = dpp_f<DPP_WAVE_ROR1>(r0); p[k] = r0 + tS[k];            \
      r1 = dpp_f<DPP_WAVE_ROR1>(r1); p[8 + k] = r1 + tS[8 + k];    \
      r2 = dpp_f<DPP_WAVE_ROR1>(r2); p[16 + k] = r2 + tS[16 + k];  \
      r3 = dpp_f<DPP_WAVE_ROR1>(r3); p[24 + k] = r3 + tS[24 + k];  \
      r4 = dpp_f<DPP_WAVE_ROR1>(r4); p[32 + k] = r4 + tS[32 + k];  \
      r5 = dpp_f<DPP_WAVE_ROR1>(r5); p[40 + k] = r5 + tS[40 + k];  \
      r6 = dpp_f<DPP_WAVE_ROR1>(r6); p[48 + k] = r6 + tS[48 + k];  \
      r7 = dpp_f<DPP_WAVE_ROR1>(r7); p[56 + k] = r7 + tS[56 + k];  \
    }                                                              \
    float best = vmax64(p);                                        \
    alpha = best + (EV);                                           \
    awsb[(t << 6) | j] = alpha;                                    \
  }
#define RELOAD(ES)                                 \
  {                                                \
    int r = t + PF; r = r > TT - 1 ? TT - 1 : r;   \
    ES = lg[r * DD + jj];                          \
  }

  int t = 1;
  while (t < L) {
    STEP(e0); RELOAD(e0); ++t; if (t >= L) break;
    STEP(e1); RELOAD(e1); ++t; if (t >= L) break;
    STEP(e2); RELOAD(e2); ++t; if (t >= L) break;
    STEP(e3); RELOAD(e3); ++t; if (t >= L) break;
    STEP(e4); RELOAD(e4); ++t; if (t >= L) break;
    STEP(e5); RELOAD(e5); ++t; if (t >= L) break;
    STEP(e6); RELOAD(e6); ++t; if (t >= L) break;
    STEP(e7); RELOAD(e7); ++t;
  }
#undef STEP
#undef RELOAD
}

// ---- kernel 2: parallel bp extraction (throughput regime) ----
__global__ __launch_bounds__(64) void crf_bpx(const float* __restrict__ aws,
                                              const int* __restrict__ lens,
                                              const float* __restrict__ trans,
                                              unsigned char* __restrict__ bpws) {
  const int gb = blockIdx.x;            // BB * 64 blocks
  const int b = gb >> 6;
  const int t0 = ((gb & 63) << 3) + 1;  // 1, 9, ..., 505
  const int L = lens[b];
  if (t0 >= L) return;                  // wave-uniform
  const int j = threadIdx.x;
  const int jj = j < DD ? j : DD - 1;

  float tcol[DD];
#pragma unroll
  for (int i = 0; i < DD; ++i) tcol[i] = trans[i * DD + jj];

#pragma unroll
  for (int k = 0; k < 8; ++k) {
    const int t = t0 + k;
    if (t >= L) break;                  // wave-uniform
    const float* ar = aws + ((size_t)b * TT + (t - 1)) * AWS_STRIDE;
    float s_[DD];
#pragma unroll
    for (int q = 0; q < 12; ++q) {
      float4 v = ((const float4*)ar)[q]; // uniform addr -> broadcast
      s_[4 * q + 0] = v.x + tcol[4 * q + 0];
      s_[4 * q + 1] = v.y + tcol[4 * q + 1];
      s_[4 * q + 2] = v.z + tcol[4 * q + 2];
      s_[4 * q + 3] = v.w + tcol[4 * q + 3];
    }
    int idx = argidx48(s_);
    if (j < DD) bpws[((size_t)b * TT + t) * DD + j] = (unsigned char)idx;
  }
}

// ---- kernel 3: backtrack (compose) + tail zero ----
__global__ __launch_bounds__(64, 1) void crf_btr(const float* __restrict__ aws,
                                                 const int* __restrict__ lens,
                                                 const unsigned char* __restrict__ bpws,
                                                 int* __restrict__ out) {
  const int b = blockIdx.x;
  const int j = threadIdx.x;
  const int jj = j < DD ? j : DD - 1;
  const int L = lens[b];

  float av = aws[((size_t)b * TT + (L - 1)) * AWS_STRIDE + jj];
  float af[DD];
#pragma unroll
  for (int i = 0; i < DD; ++i) af[i] = readlane_f(av, i);
  const int btag = argidx48(af);

  int* ob = out + (size_t)b * TT;
  if (j == 0) ob[L - 1] = btag;

  const unsigned char* bpb = bpws + (size_t)b * TT * DD;
#define BPROW(T) (int)bpb[((T) > 0 ? (T) : 0) * DD + jj]
  int v0 = BPROW(L - 1), v1 = BPROW(L - 2), v2 = BPROW(L - 3), v3 = BPROW(L - 4),
      v4 = BPROW(L - 5), v5 = BPROW(L - 6), v6 = BPROW(L - 7), v7 = BPROW(L - 8);

  int H = j;
  int t = L - 1;
#define CSTEP(VS)                                  \
  {                                                \
    H = __shfl((VS), H, 64);                       \
    if (j == btag) ob[t - 1] = H;                  \
    VS = BPROW(t - 8);                             \
    --t;                                           \
  }
  while (t >= 1) {
    CSTEP(v0); if (t < 1) break;
    CSTEP(v1); if (t < 1) break;
    CSTEP(v2); if (t < 1) break;
    CSTEP(v3); if (t < 1) break;
    CSTEP(v4); if (t < 1) break;
    CSTEP(v5); if (t < 1) break;
    CSTEP(v6); if (t < 1) break;
    CSTEP(v7);
  }
#undef CSTEP
#undef BPROW

  for (int tt = L + j; tt < TT; tt += 64) ob[tt] = 0;
}

// ---- fallback (ws too small): R16 single-kernel ----
__global__ __launch_bounds__(64, 1) void crf_fallback(const float* __restrict__ logits,
                                                      const int* __restrict__ lens,
                                                      const float* __restrict__ trans,
                                                      int* __restrict__ out) {
  const int b = blockIdx.x;
  const int j = threadIdx.x;
  const int jj = j < DD ? j : DD - 1;
  __shared__ unsigned char bp[TT * 64];

  float tcol[DD];
#pragma unroll
  for (int i = 0; i < DD; ++i) tcol[i] = trans[i * DD + jj];
  const float* lg = logits + (size_t)b * TT * DD;
  const int L = lens[b];
  float alpha = lg[jj];

  float e0 = lg[1 * DD + jj], e1 = lg[2 * DD + jj],
        e2 = lg[3 * DD + jj], e3 = lg[4 * DD + jj],
        e4 = lg[5 * DD + jj], e5 = lg[6 * DD + jj],
        e6 = lg[7 * DD + jj], e7 = lg[8 * DD + jj];

#define STEP(EV)                                                         \
  {                                                                      \
    float s_[DD];                                                        \
    _Pragma("unroll")                                                    \
    for (int i = 0; i < DD; ++i) s_[i] = readlane_f(alpha, i) + tcol[i]; \
    float best = vmax48(s_);                                             \
    int idx = argidx48(s_);                                              \
    alpha = best + (EV);                                                 \
    bp[t * 64 + j] = (unsigned char)idx;                                 \
  }
#define RELOAD(ES)                                 \
  {                                                \
    int r = t + PF; r = r > TT - 1 ? TT - 1 : r;   \
    ES = lg[r * DD + jj];                          \
  }
  int t = 1;
  while (t < L) {
    STEP(e0); RELOAD(e0); ++t; if (t >= L) break;
    STEP(e1); RELOAD(e1); ++t; if (t >= L) break;
    STEP(e2); RELOAD(e2); ++t; if (t >= L) break;
    STEP(e3); RELOAD(e3); ++t; if (t >= L) break;
    STEP(e4); RELOAD(e4); ++t; if (t >= L) break;
    STEP(e5); RELOAD(e5); ++t; if (t >= L) break;
    STEP(e6); RELOAD(e6); ++t; if (t >= L) break;
    STEP(e7); RELOAD(e7); ++t;
  }
#undef STEP
#undef RELOAD
  __syncthreads();

  float af[DD];
#pragma unroll
  for (int i = 0; i < DD; ++i) af[i] = readlane_f(alpha, i);
  int btag = argidx48(af);
  int* ob = out + (size_t)b * TT;
  if (j == 0) ob[L - 1] = btag;
  int H = j;
  for (int tt = L - 1; tt >= 1; --tt) {
    int v = bp[tt * 64 + jj];
    H = __shfl(v, H, 64);
    if (j == btag) ob[tt - 1] = H;
  }
  for (int tt = L + j; tt < TT; tt += 64) ob[tt] = 0;
}

extern "C" void kernel_launch(void* const* d_in, const int* in_sizes, int n_in,
                              void* d_out, int out_size, void* d_ws, size_t ws_size,
                              hipStream_t stream) {
  const float* logits = (const float*)d_in[0];
  const int* lens     = (const int*)d_in[1];
  const float* trans  = (const float*)d_in[2];
  int* out            = (int*)d_out;
  (void)in_sizes; (void)n_in; (void)out_size;

  if (ws_size >= WS_NEED) {
    float* aws = (float*)d_ws;
    unsigned char* bpws = (unsigned char*)d_ws + AWS_BYTES;
    crf_fwd<<<BB, 64, 0, stream>>>(logits, lens, trans, aws);
    crf_bpx<<<BB * 64, 64, 0, stream>>>(aws, lens, trans, bpws);
    crf_btr<<<BB, 64, 0, stream>>>(aws, lens, bpws, out);
  } else {
    crf_fallback<<<BB, 64, 0, stream>>>(logits, lens, trans, out);
  }
}

// Round 20
// 266.505 us; speedup vs baseline: 1.1249x; 1.1249x over previous
//
#include <hip/hip_runtime.h>

#define DD 48
#define TT 512
#define BB 512
#define PF 8
#define AWS_STRIDE 64
#define AWS_BYTES ((size_t)BB * TT * AWS_STRIDE * 4)   // 67,108,864
#define WS_NEED AWS_BYTES

__device__ __forceinline__ float readlane_f(float v, int lane) {
  return __int_as_float(__builtin_amdgcn_readlane(__float_as_int(v), lane));
}
__device__ __forceinline__ float max3f(float a, float b, float c) {
  return fmaxf(fmaxf(a, b), c);
}

// pure value max over 48 (VCC-free, fuses to v_max3_f32)
__device__ __forceinline__ float vmax48(const float* s) {
  float m1[16];
#pragma unroll
  for (int k = 0; k < 16; ++k) m1[k] = max3f(s[3 * k], s[3 * k + 1], s[3 * k + 2]);
  float m2[6];
#pragma unroll
  for (int k = 0; k < 5; ++k) m2[k] = max3f(m1[3 * k], m1[3 * k + 1], m1[3 * k + 2]);
  m2[5] = m1[15];
  return fmaxf(max3f(m2[0], m2[1], m2[2]), max3f(m2[3], m2[4], m2[5]));
}

// argmax with first-index ties (strict > moves right)
__device__ __forceinline__ int argidx48(const float* s) {
  float v1[24]; int x1[24];
#pragma unroll
  for (int k = 0; k < 24; ++k) {
    float l = s[2 * k], r = s[2 * k + 1];
    v1[k] = fmaxf(l, r); x1[k] = (r > l) ? 2 * k + 1 : 2 * k;
  }
  float v2[12]; int x2[12];
#pragma unroll
  for (int k = 0; k < 12; ++k) {
    float l = v1[2 * k], r = v1[2 * k + 1];
    v2[k] = fmaxf(l, r); x2[k] = (r > l) ? x1[2 * k + 1] : x1[2 * k];
  }
  float v3[6]; int x3[6];
#pragma unroll
  for (int k = 0; k < 6; ++k) {
    float l = v2[2 * k], r = v2[2 * k + 1];
    v3[k] = fmaxf(l, r); x3[k] = (r > l) ? x2[2 * k + 1] : x2[2 * k];
  }
  float v4[3]; int x4[3];
#pragma unroll
  for (int k = 0; k < 3; ++k) {
    float l = v3[2 * k], r = v3[2 * k + 1];
    v4[k] = fmaxf(l, r); x4[k] = (r > l) ? x3[2 * k + 1] : x3[2 * k];
  }
  float vm = fmaxf(v4[0], v4[1]);
  int xm = (v4[1] > v4[0]) ? x4[1] : x4[0];
  return (v4[2] > vm) ? x4[2] : xm;
}

// ---- fused per-batch pipeline: fwd (wave0) -> bpx (4 waves) -> btr (wave0) ----
__global__ __launch_bounds__(256, 1) void crf_fused(const float* __restrict__ logits,
                                                    const int* __restrict__ lens,
                                                    const float* __restrict__ trans,
                                                    float* __restrict__ aws,
                                                    int* __restrict__ out) {
  const int b = blockIdx.x;
  const int tid = threadIdx.x;
  const int j = tid & 63;
  const int wave = tid >> 6;           // 0..3
  const int jj = j < DD ? j : DD - 1;

  __shared__ unsigned char bp[TT * 64]; // 32 KB backpointers

  float tcol[DD];
#pragma unroll
  for (int i = 0; i < DD; ++i) tcol[i] = trans[i * DD + jj];

  const float* lg = logits + (size_t)b * TT * DD;
  const int L = lens[b];
  float* awsb = aws + (size_t)b * TT * AWS_STRIDE;

  float alpha = lg[jj]; // wave0's copy is authoritative after fwd

  // ---- phase A: serial forward (wave0 only; others sleep at the barrier) ----
  if (wave == 0) {
    __builtin_amdgcn_s_setprio(1);     // shield the serial chain from co-resident blocks
    awsb[j] = alpha;                   // row 0

    float e0 = lg[1 * DD + jj], e1 = lg[2 * DD + jj],
          e2 = lg[3 * DD + jj], e3 = lg[4 * DD + jj],
          e4 = lg[5 * DD + jj], e5 = lg[6 * DD + jj],
          e6 = lg[7 * DD + jj], e7 = lg[8 * DD + jj];

#define STEP(EV)                                                    \
    {                                                               \
      float a_[DD];                                                 \
      _Pragma("unroll")                                             \
      for (int i = 0; i < DD; ++i) a_[i] = readlane_f(alpha, i);    \
      float s_[DD];                                                 \
      _Pragma("unroll")                                             \
      for (int i = 0; i < DD; ++i) s_[i] = a_[i] + tcol[i];         \
      float best = vmax48(s_);                                      \
      alpha = best + (EV);                                          \
      awsb[(t << 6) | j] = alpha;                                   \
    }
#define RELOAD(ES)                                 \
    {                                              \
      int r = t + PF; r = r > TT - 1 ? TT - 1 : r; \
      ES = lg[r * DD + jj];                        \
    }

    int t = 1;
    while (t < L) {
      STEP(e0); RELOAD(e0); ++t; if (t >= L) break;
      STEP(e1); RELOAD(e1); ++t; if (t >= L) break;
      STEP(e2); RELOAD(e2); ++t; if (t >= L) break;
      STEP(e3); RELOAD(e3); ++t; if (t >= L) break;
      STEP(e4); RELOAD(e4); ++t; if (t >= L) break;
      STEP(e5); RELOAD(e5); ++t; if (t >= L) break;
      STEP(e6); RELOAD(e6); ++t; if (t >= L) break;
      STEP(e7); RELOAD(e7); ++t;
    }
#undef STEP
#undef RELOAD
    __builtin_amdgcn_s_setprio(0);
    __threadfence();                   // drain alpha-row stores to L2
  }
  __syncthreads();                     // alpha rows visible to all waves

  // ---- phase B: bp extraction, 4 waves split this batch's tasks ----
  for (int t = 1 + wave; t < L; t += 4) {
    const float* ar = awsb + ((t - 1) << 6);
    float s_[DD];
#pragma unroll
    for (int q = 0; q < 12; ++q) {
      float4 v = ((const float4*)ar)[q]; // uniform addr -> broadcast (L2-hot)
      s_[4 * q + 0] = v.x + tcol[4 * q + 0];
      s_[4 * q + 1] = v.y + tcol[4 * q + 1];
      s_[4 * q + 2] = v.z + tcol[4 * q + 2];
      s_[4 * q + 3] = v.w + tcol[4 * q + 3];
    }
    int idx = argidx48(s_);
    bp[(t << 6) | j] = (unsigned char)idx;
  }
  __syncthreads();                     // bp complete

  // ---- phase C: backtrack (wave0) + tail zero (all) ----
  int* ob = out + (size_t)b * TT;
  if (wave == 0) {
    float af[DD];
#pragma unroll
    for (int i = 0; i < DD; ++i) af[i] = readlane_f(alpha, i);
    const int btag = argidx48(af);
    if (j == 0) ob[L - 1] = btag;

    int H = j;
    for (int tt = L - 1; tt >= 1; --tt) {
      int v = bp[(tt << 6) | jj];      // addr independent of H -> pipelined
      H = __shfl(v, H, 64);            // H' = bp_t[H]
      if (j == btag) ob[tt - 1] = H;
    }
  }
  for (int tt = L + tid; tt < TT; tt += 256) ob[tt] = 0;
}

// ---- fallback (ws too small): proven single-kernel (R16-style) ----
__global__ __launch_bounds__(64, 1) void crf_fallback(const float* __restrict__ logits,
                                                      const int* __restrict__ lens,
                                                      const float* __restrict__ trans,
                                                      int* __restrict__ out) {
  const int b = blockIdx.x;
  const int j = threadIdx.x;
  const int jj = j < DD ? j : DD - 1;
  __shared__ unsigned char bp[TT * 64];

  float tcol[DD];
#pragma unroll
  for (int i = 0; i < DD; ++i) tcol[i] = trans[i * DD + jj];
  const float* lg = logits + (size_t)b * TT * DD;
  const int L = lens[b];
  float alpha = lg[jj];

  float e0 = lg[1 * DD + jj], e1 = lg[2 * DD + jj],
        e2 = lg[3 * DD + jj], e3 = lg[4 * DD + jj],
        e4 = lg[5 * DD + jj], e5 = lg[6 * DD + jj],
        e6 = lg[7 * DD + jj], e7 = lg[8 * DD + jj];

#define STEP(EV)                                                         \
  {                                                                      \
    float s_[DD];                                                        \
    _Pragma("unroll")                                                    \
    for (int i = 0; i < DD; ++i) s_[i] = readlane_f(alpha, i) + tcol[i]; \
    float best = vmax48(s_);                                             \
    int idx = argidx48(s_);                                              \
    alpha = best + (EV);                                                 \
    bp[t * 64 + j] = (unsigned char)idx;                                 \
  }
#define RELOAD(ES)                                 \
  {                                                \
    int r = t + PF; r = r > TT - 1 ? TT - 1 : r;   \
    ES = lg[r * DD + jj];                          \
  }
  int t = 1;
  while (t < L) {
    STEP(e0); RELOAD(e0); ++t; if (t >= L) break;
    STEP(e1); RELOAD(e1); ++t; if (t >= L) break;
    STEP(e2); RELOAD(e2); ++t; if (t >= L) break;
    STEP(e3); RELOAD(e3); ++t; if (t >= L) break;
    STEP(e4); RELOAD(e4); ++t; if (t >= L) break;
    STEP(e5); RELOAD(e5); ++t; if (t >= L) break;
    STEP(e6); RELOAD(e6); ++t; if (t >= L) break;
    STEP(e7); RELOAD(e7); ++t;
  }
#undef STEP
#undef RELOAD
  __syncthreads();

  float af[DD];
#pragma unroll
  for (int i = 0; i < DD; ++i) af[i] = readlane_f(alpha, i);
  int btag = argidx48(af);
  int* ob = out + (size_t)b * TT;
  if (j == 0) ob[L - 1] = btag;
  int H = j;
  for (int tt = L - 1; tt >= 1; --tt) {
    int v = bp[tt * 64 + jj];
    H = __shfl(v, H, 64);
    if (j == btag) ob[tt - 1] = H;
  }
  for (int tt = L + j; tt < TT; tt += 64) ob[tt] = 0;
}

extern "C" void kernel_launch(void* const* d_in, const int* in_sizes, int n_in,
                              void* d_out, int out_size, void* d_ws, size_t ws_size,
                              hipStream_t stream) {
  const float* logits = (const float*)d_in[0];
  const int* lens     = (const int*)d_in[1];
  const float* trans  = (const float*)d_in[2];
  int* out            = (int*)d_out;
  (void)in_sizes; (void)n_in; (void)out_size;

  if (ws_size >= WS_NEED) {
    float* aws = (float*)d_ws;
    crf_fused<<<BB, 256, 0, stream>>>(logits, lens, trans, aws, out);
  } else {
    crf_fallback<<<BB, 64, 0, stream>>>(logits, lens, trans, out);
  }
}